// Round 1
// baseline (388.258 us; speedup 1.0000x reference)
//
#include <hip/hip_runtime.h>

// RETRO chunked cross-attention, MI355X bf16 MFMA pipeline.
// B=4 S=2048 D=1024 H=16 DK=64 CL=64 C=32 N=2 NL=128
// Stages: transpose weights -> LN(shifted h) -> cast e -> GEMM Q/K/V ->
//         per-(b,c,h) attention -> GEMM O w/ residual+shift epilogue -> prologue copy.

typedef __attribute__((ext_vector_type(8))) short short8;
typedef __attribute__((ext_vector_type(4))) float f32x4;
typedef unsigned short ushort_t;

__device__ inline ushort_t f2bf(float f) {
  union { float f; unsigned int u; } v; v.f = f;
  unsigned int u = v.u;
  return (ushort_t)((u + 0x7fffu + ((u >> 16) & 1u)) >> 16);
}

__device__ inline void gl_lds16(const void* g, void* l) {
  __builtin_amdgcn_global_load_lds(
      (const __attribute__((address_space(1))) unsigned int*)g,
      (__attribute__((address_space(3))) unsigned int*)l, 16, 0, 0);
}

// ---------------- weight transpose + bf16 cast: WT[n][k] = W[k][n] ----------
__global__ void transpose_w(const float* __restrict__ W, ushort_t* __restrict__ WT) {
  __shared__ float tile[32][33];
  int k0 = blockIdx.x * 32, n0 = blockIdx.y * 32;
  int c = threadIdx.x & 31, r = threadIdx.x >> 5;  // r in 0..7
#pragma unroll
  for (int p = 0; p < 4; p++)
    tile[r + p * 8][c] = W[(size_t)(k0 + r + p * 8) * 1024 + n0 + c];
  __syncthreads();
#pragma unroll
  for (int p = 0; p < 4; p++)
    WT[(size_t)(n0 + r + p * 8) * 1024 + k0 + c] = f2bf(tile[c][r + p * 8]);
}

// ---------------- shifted LayerNorm -> bf16 query rows ----------------------
// hb row j (per b): j<1985 -> LN(h[b][j+63]); else zeros (padded rows).
__global__ void ln_kernel(const float* __restrict__ h, const float* __restrict__ g,
                          const float* __restrict__ bb, ushort_t* __restrict__ hb) {
  int row = blockIdx.x;            // 0..8191
  int b = row >> 11, jj = row & 2047;
  int t = threadIdx.x;
  ushort_t* dst = hb + (size_t)row * 1024;
  if (jj >= 1985) {
    ((unsigned int*)dst)[t] = 0u;
    ((unsigned int*)dst)[t + 256] = 0u;
    return;
  }
  const float* src = h + ((size_t)(b << 11) + jj + 63) * 1024;
  f32x4 x = *(const f32x4*)&src[t * 4];
  float s = x[0] + x[1] + x[2] + x[3];
  float sq = x[0]*x[0] + x[1]*x[1] + x[2]*x[2] + x[3]*x[3];
#pragma unroll
  for (int off = 32; off > 0; off >>= 1) {
    s  += __shfl_xor(s, off);
    sq += __shfl_xor(sq, off);
  }
  __shared__ float red[8];
  if ((t & 63) == 0) { red[(t >> 6) * 2] = s; red[(t >> 6) * 2 + 1] = sq; }
  __syncthreads();
  float sum = red[0] + red[2] + red[4] + red[6];
  float sumsq = red[1] + red[3] + red[5] + red[7];
  float mu = sum * (1.f / 1024.f);
  float var = sumsq * (1.f / 1024.f) - mu * mu;
  float rs = rsqrtf(var + 1e-5f);
  f32x4 gg = *(const f32x4*)&g[t * 4];
  f32x4 bv = *(const f32x4*)&bb[t * 4];
  ushort_t o0 = f2bf((x[0] - mu) * rs * gg[0] + bv[0]);
  ushort_t o1 = f2bf((x[1] - mu) * rs * gg[1] + bv[1]);
  ushort_t o2 = f2bf((x[2] - mu) * rs * gg[2] + bv[2]);
  ushort_t o3 = f2bf((x[3] - mu) * rs * gg[3] + bv[3]);
  unsigned long long pack = (unsigned long long)o0 | ((unsigned long long)o1 << 16)
                          | ((unsigned long long)o2 << 32) | ((unsigned long long)o3 << 48);
  *(unsigned long long*)&dst[t * 4] = pack;
}

// ---------------- f32 -> bf16 cast (vector) ---------------------------------
__global__ void conv_bf16(const float* __restrict__ s, ushort_t* __restrict__ d, int n8) {
  int i = blockIdx.x * 256 + threadIdx.x;
  if (i >= n8) return;
  const f32x4* sp = (const f32x4*)(s + (size_t)i * 8);
  f32x4 a = sp[0], b = sp[1];
  short8 o;
  o[0] = (short)f2bf(a[0]); o[1] = (short)f2bf(a[1]);
  o[2] = (short)f2bf(a[2]); o[3] = (short)f2bf(a[3]);
  o[4] = (short)f2bf(b[0]); o[5] = (short)f2bf(b[1]);
  o[6] = (short)f2bf(b[2]); o[7] = (short)f2bf(b[3]);
  *(short8*)(d + (size_t)i * 8) = o;
}

// ---------------- GEMM: C[M x 1024] = A[M x 1024] @ BT^T + bias -------------
// m97 structure: 128x128 tile, 4 waves (2x2 of 64x64), BK=32, 16x16x32 MFMA.
// EPI 0: bf16 out.  EPI 1: f32 out + residual + shifted store (skip j>=1985).
template <int EPI>
__launch_bounds__(256, 2)
__global__ void gemm_bt(const ushort_t* __restrict__ A, const ushort_t* __restrict__ BT,
                        const float* __restrict__ bias, ushort_t* __restrict__ Cb,
                        float* __restrict__ Cf, const float* __restrict__ resid) {
  constexpr int K = 1024;
  __shared__ __attribute__((aligned(16))) ushort_t As[128 * 32];
  __shared__ __attribute__((aligned(16))) ushort_t Bs[128 * 32];
  const int tm = blockIdx.x * 128, tn = blockIdx.y * 128;
  const int t = threadIdx.x, lane = t & 63, wv = t >> 6;
  const int wm = (wv >> 1) * 64, wn = (wv & 1) * 64;
  const int row = lane & 15, kg = (lane >> 4) * 8;
  f32x4 acc[4][4] = {};
  const int r0 = t >> 2, ko = (t & 3) * 8;
  const ushort_t* Ap = A + (size_t)(tm + r0) * K + ko;
  const ushort_t* Bp = BT + (size_t)(tn + r0) * K + ko;
  for (int k0 = 0; k0 < K; k0 += 32) {
    gl_lds16(Ap + k0, &As[t * 8]);
    gl_lds16(Ap + 64 * K + k0, &As[(t + 256) * 8]);
    gl_lds16(Bp + k0, &Bs[t * 8]);
    gl_lds16(Bp + 64 * K + k0, &Bs[(t + 256) * 8]);
    __syncthreads();
    short8 af[4], bf[4];
#pragma unroll
    for (int m = 0; m < 4; m++) af[m] = *(const short8*)&As[(wm + m * 16 + row) * 32 + kg];
#pragma unroll
    for (int n = 0; n < 4; n++) bf[n] = *(const short8*)&Bs[(wn + n * 16 + row) * 32 + kg];
#pragma unroll
    for (int m = 0; m < 4; m++)
#pragma unroll
      for (int n = 0; n < 4; n++)
        acc[m][n] = __builtin_amdgcn_mfma_f32_16x16x32_bf16(af[m], bf[n], acc[m][n], 0, 0, 0);
    __syncthreads();
  }
  const int cr = (lane >> 4) * 4, cc = lane & 15;
#pragma unroll
  for (int m = 0; m < 4; m++) {
#pragma unroll
    for (int n = 0; n < 4; n++) {
      int col = tn + wn + n * 16 + cc;
      float bsv = bias[col];
#pragma unroll
      for (int j = 0; j < 4; j++) {
        int rg = tm + wm + m * 16 + cr + j;
        float v = acc[m][n][j] + bsv;
        if (EPI == 0) {
          Cb[(size_t)rg * 1024 + col] = f2bf(v);
        } else {
          int b = rg >> 11, jj = rg & 2047;
          if (jj < 1985) {
            size_t oi = ((size_t)(b << 11) + jj + 63) * 1024 + col;
            Cf[oi] = v + resid[oi];
          }
        }
      }
    }
  }
}

// ---------------- attention: one block per (b,c,h) --------------------------
// Q[64x64] @ K[256x64]^T -> softmax(256) -> @ V[256x64] -> O[64x64]
__launch_bounds__(256, 1)
__global__ void attn_kernel(const ushort_t* __restrict__ Q, const ushort_t* __restrict__ Kb,
                            const ushort_t* __restrict__ Vb, ushort_t* __restrict__ Ob) {
  __shared__ __attribute__((aligned(16))) ushort_t Qs[64 * 64];
  __shared__ __attribute__((aligned(16))) ushort_t Ks[256 * 64];
  __shared__ __attribute__((aligned(16))) ushort_t Vt[64 * 264];   // padded stride
  __shared__ __attribute__((aligned(16))) float Sf[64 * 260];      // padded stride
  ushort_t* Pb = (ushort_t*)Sf;  // P[64][264] bf16 overlays Sf after barrier

  const int hh = blockIdx.x, cch = blockIdx.y, b = blockIdx.z;
  const int t = threadIdx.x, lane = t & 63, wv = t >> 6;
  const size_t qbase = ((size_t)(b * 32 + cch) * 64) * 1024 + hh * 64;
  const size_t kvbase = ((size_t)(b * 32 + cch) * 256) * 1024 + hh * 64;

  // Q: 512 16B chunks (2/thread), row-major [64][64]
  gl_lds16(Q + qbase + (size_t)(t >> 3) * 1024 + (t & 7) * 8, &Qs[t * 8]);
  {
    int c1 = t + 256;
    gl_lds16(Q + qbase + (size_t)(c1 >> 3) * 1024 + (c1 & 7) * 8, &Qs[c1 * 8]);
  }
  // K: 2048 chunks (8/thread), row-major [256][64]
#pragma unroll
  for (int p = 0; p < 8; p++) {
    int ch = t + 256 * p;
    gl_lds16(Kb + kvbase + (size_t)(ch >> 3) * 1024 + (ch & 7) * 8, &Ks[ch * 8]);
  }
  // V transposed into Vt[d][j] (stride 264)
#pragma unroll
  for (int p = 0; p < 8; p++) {
    int ch = t + 256 * p;
    int j = ch >> 3, d0 = (ch & 7) * 8;
    short8 vv = *(const short8*)(Vb + kvbase + (size_t)j * 1024 + d0);
#pragma unroll
    for (int ii = 0; ii < 8; ii++) Vt[(d0 + ii) * 264 + j] = (ushort_t)vv[ii];
  }
  __syncthreads();

  const int row = lane & 15, kg = (lane >> 4) * 8;
  // S = Q @ K^T ; wave wv covers kv cols [wv*64, wv*64+64)
  {
    f32x4 accs[4][4] = {};
#pragma unroll
    for (int kk = 0; kk < 64; kk += 32) {
      short8 af[4], bf[4];
#pragma unroll
      for (int m = 0; m < 4; m++) af[m] = *(const short8*)&Qs[(m * 16 + row) * 64 + kk + kg];
#pragma unroll
      for (int n = 0; n < 4; n++)
        bf[n] = *(const short8*)&Ks[(wv * 64 + n * 16 + row) * 64 + kk + kg];
#pragma unroll
      for (int m = 0; m < 4; m++)
#pragma unroll
        for (int n = 0; n < 4; n++)
          accs[m][n] = __builtin_amdgcn_mfma_f32_16x16x32_bf16(af[m], bf[n], accs[m][n], 0, 0, 0);
    }
    const int cr = (lane >> 4) * 4, cc = lane & 15;
#pragma unroll
    for (int m = 0; m < 4; m++)
#pragma unroll
      for (int n = 0; n < 4; n++)
#pragma unroll
        for (int j = 0; j < 4; j++)
          Sf[(m * 16 + cr + j) * 260 + wv * 64 + n * 16 + cc] = accs[m][n][j];
  }
  __syncthreads();

  // softmax over 256, 4 threads per row (r = t>>2, cols q+4i)
  float ev[64];
  float inv;
  {
    const int r = t >> 2, q = t & 3;
    float mx = -1e30f;
#pragma unroll
    for (int i = 0; i < 64; i++) mx = fmaxf(mx, Sf[r * 260 + q + 4 * i]);
    mx = fmaxf(mx, __shfl_xor(mx, 1));
    mx = fmaxf(mx, __shfl_xor(mx, 2));
    float sum = 0.f;
#pragma unroll
    for (int i = 0; i < 64; i++) {
      float e = __expf((Sf[r * 260 + q + 4 * i] - mx) * 0.125f);
      ev[i] = e;
      sum += e;
    }
    sum += __shfl_xor(sum, 1);
    sum += __shfl_xor(sum, 2);
    inv = 1.f / sum;
  }
  __syncthreads();  // all Sf reads done; safe to overlay P
  {
    const int r = t >> 2, q = t & 3;
#pragma unroll
    for (int i = 0; i < 64; i++) Pb[r * 264 + q + 4 * i] = f2bf(ev[i] * inv);
  }
  __syncthreads();

  // O = P @ V ; wave wv covers d cols [wv*16, wv*16+16)
  {
    f32x4 acco[4] = {};
#pragma unroll
    for (int kt = 0; kt < 8; kt++) {
      short8 bfv = *(const short8*)&Vt[(wv * 16 + row) * 264 + kt * 32 + kg];
#pragma unroll
      for (int m = 0; m < 4; m++) {
        short8 af = *(const short8*)&Pb[(m * 16 + row) * 264 + kt * 32 + kg];
        acco[m] = __builtin_amdgcn_mfma_f32_16x16x32_bf16(af, bfv, acco[m], 0, 0, 0);
      }
    }
    const int cr = (lane >> 4) * 4, cc = lane & 15;
    size_t obase = ((size_t)(b * 32 + cch) * 64) * 1024 + hh * 64 + wv * 16 + cc;
#pragma unroll
    for (int m = 0; m < 4; m++)
#pragma unroll
      for (int j = 0; j < 4; j++)
        Ob[obase + (size_t)(m * 16 + cr + j) * 1024] = f2bf(acco[m][j]);
  }
}

// ---------------- residual-only prologue rows t < 63 ------------------------
__global__ void copy_prologue(const float* __restrict__ h, float* __restrict__ out) {
  int tt = blockIdx.x;  // 0..251
  int b = tt / 63, r = tt % 63;
  size_t idx = ((size_t)(b * 2048) + r) * 1024 + threadIdx.x * 4;
  *(f32x4*)&out[idx] = *(const f32x4*)&h[idx];
}

extern "C" void kernel_launch(void* const* d_in, const int* in_sizes, int n_in,
                              void* d_out, int out_size, void* d_ws, size_t ws_size,
                              hipStream_t stream) {
  const float* h    = (const float*)d_in[0];
  const float* e    = (const float*)d_in[1];
  const float* ln_g = (const float*)d_in[2];
  const float* ln_b = (const float*)d_in[3];
  const float* Wq   = (const float*)d_in[4];
  const float* bq   = (const float*)d_in[5];
  const float* Wk   = (const float*)d_in[6];
  const float* bk   = (const float*)d_in[7];
  const float* Wv   = (const float*)d_in[8];
  const float* bv   = (const float*)d_in[9];
  const float* Wo   = (const float*)d_in[10];
  const float* bo   = (const float*)d_in[11];
  float* out = (float*)d_out;

  char* ws = (char*)d_ws;
  const size_t MB = 1024 * 1024;
  ushort_t* WqT  = (ushort_t*)(ws + 0 * MB);
  ushort_t* WkT  = (ushort_t*)(ws + 2 * MB);
  ushort_t* WvT  = (ushort_t*)(ws + 4 * MB);
  ushort_t* WoT  = (ushort_t*)(ws + 6 * MB);
  ushort_t* hb   = (ushort_t*)(ws + 8 * MB);    // 16 MB
  ushort_t* e_bf = (ushort_t*)(ws + 24 * MB);   // 64 MB
  ushort_t* Qb   = (ushort_t*)(ws + 88 * MB);   // 16 MB
  ushort_t* Kbuf = (ushort_t*)(ws + 104 * MB);  // 64 MB
  ushort_t* Vbuf = (ushort_t*)(ws + 168 * MB);  // 64 MB
  ushort_t* Obuf = (ushort_t*)(ws + 232 * MB);  // 16 MB -> total 248 MB

  dim3 g32(32, 32);
  transpose_w<<<g32, 256, 0, stream>>>(Wq, WqT);
  transpose_w<<<g32, 256, 0, stream>>>(Wk, WkT);
  transpose_w<<<g32, 256, 0, stream>>>(Wv, WvT);
  transpose_w<<<g32, 256, 0, stream>>>(Wo, WoT);

  ln_kernel<<<8192, 256, 0, stream>>>(h, ln_g, ln_b, hb);
  conv_bf16<<<16384, 256, 0, stream>>>(e, e_bf, 4194304);  // 32768*1024/8

  gemm_bt<0><<<dim3(64, 8), 256, 0, stream>>>(hb, WqT, bq, Qb, nullptr, nullptr);
  gemm_bt<0><<<dim3(256, 8), 256, 0, stream>>>(e_bf, WkT, bk, Kbuf, nullptr, nullptr);
  gemm_bt<0><<<dim3(256, 8), 256, 0, stream>>>(e_bf, WvT, bv, Vbuf, nullptr, nullptr);

  attn_kernel<<<dim3(16, 32, 4), 256, 0, stream>>>(Qb, Kbuf, Vbuf, Obuf);

  gemm_bt<1><<<dim3(64, 8), 256, 0, stream>>>(Obuf, WoT, bo, nullptr, out, h);
  copy_prologue<<<252, 256, 0, stream>>>(h, out);
}

// Round 2
// 363.780 us; speedup vs baseline: 1.0673x; 1.0673x over previous
//
#include <hip/hip_runtime.h>

// RETRO chunked cross-attention, MI355X bf16 MFMA pipeline. Round 2:
//  - fused K+V projection GEMM (shared A staging, 32 MFMA/K-step)
//  - 1-D grids with XCD chunk swizzle, N-fastest tile order (A-panel L2 reuse)
//  - attention: XOR-swizzled Q/K LDS (kills 16-way conflicts), bf16 S overlay
//    (74 KB LDS -> 2 blocks/CU), vectorized softmax.

typedef __attribute__((ext_vector_type(8))) short short8;
typedef __attribute__((ext_vector_type(4))) float f32x4;
typedef unsigned short ushort_t;

__device__ inline ushort_t f2bf(float f) {
  union { float f; unsigned int u; } v; v.f = f;
  unsigned int u = v.u;
  return (ushort_t)((u + 0x7fffu + ((u >> 16) & 1u)) >> 16);
}
__device__ inline float bf2f(ushort_t s) {
  union { unsigned int u; float f; } v; v.u = ((unsigned int)s) << 16;
  return v.f;
}

__device__ inline void gl_lds16(const void* g, void* l) {
  __builtin_amdgcn_global_load_lds(
      (const __attribute__((address_space(1))) unsigned int*)g,
      (__attribute__((address_space(3))) unsigned int*)l, 16, 0, 0);
}

// ---------------- weight transpose + bf16 cast: WT[n][k] = W[k][n] ----------
__global__ void transpose_w(const float* __restrict__ W, ushort_t* __restrict__ WT) {
  __shared__ float tile[32][33];
  int k0 = blockIdx.x * 32, n0 = blockIdx.y * 32;
  int c = threadIdx.x & 31, r = threadIdx.x >> 5;  // r in 0..7
#pragma unroll
  for (int p = 0; p < 4; p++)
    tile[r + p * 8][c] = W[(size_t)(k0 + r + p * 8) * 1024 + n0 + c];
  __syncthreads();
#pragma unroll
  for (int p = 0; p < 4; p++)
    WT[(size_t)(n0 + r + p * 8) * 1024 + k0 + c] = f2bf(tile[c][r + p * 8]);
}

// ---------------- shifted LayerNorm -> bf16 query rows ----------------------
__global__ void ln_kernel(const float* __restrict__ h, const float* __restrict__ g,
                          const float* __restrict__ bb, ushort_t* __restrict__ hb) {
  int row = blockIdx.x;            // 0..8191
  int b = row >> 11, jj = row & 2047;
  int t = threadIdx.x;
  ushort_t* dst = hb + (size_t)row * 1024;
  if (jj >= 1985) {
    ((unsigned int*)dst)[t] = 0u;
    ((unsigned int*)dst)[t + 256] = 0u;
    return;
  }
  const float* src = h + ((size_t)(b << 11) + jj + 63) * 1024;
  f32x4 x = *(const f32x4*)&src[t * 4];
  float s = x[0] + x[1] + x[2] + x[3];
  float sq = x[0]*x[0] + x[1]*x[1] + x[2]*x[2] + x[3]*x[3];
#pragma unroll
  for (int off = 32; off > 0; off >>= 1) {
    s  += __shfl_xor(s, off);
    sq += __shfl_xor(sq, off);
  }
  __shared__ float red[8];
  if ((t & 63) == 0) { red[(t >> 6) * 2] = s; red[(t >> 6) * 2 + 1] = sq; }
  __syncthreads();
  float sum = red[0] + red[2] + red[4] + red[6];
  float sumsq = red[1] + red[3] + red[5] + red[7];
  float mu = sum * (1.f / 1024.f);
  float var = sumsq * (1.f / 1024.f) - mu * mu;
  float rs = rsqrtf(var + 1e-5f);
  f32x4 gg = *(const f32x4*)&g[t * 4];
  f32x4 bv = *(const f32x4*)&bb[t * 4];
  ushort_t o0 = f2bf((x[0] - mu) * rs * gg[0] + bv[0]);
  ushort_t o1 = f2bf((x[1] - mu) * rs * gg[1] + bv[1]);
  ushort_t o2 = f2bf((x[2] - mu) * rs * gg[2] + bv[2]);
  ushort_t o3 = f2bf((x[3] - mu) * rs * gg[3] + bv[3]);
  unsigned long long pack = (unsigned long long)o0 | ((unsigned long long)o1 << 16)
                          | ((unsigned long long)o2 << 32) | ((unsigned long long)o3 << 48);
  *(unsigned long long*)&dst[t * 4] = pack;
}

// ---------------- f32 -> bf16 cast (vector) ---------------------------------
__global__ void conv_bf16(const float* __restrict__ s, ushort_t* __restrict__ d, int n8) {
  int i = blockIdx.x * 256 + threadIdx.x;
  if (i >= n8) return;
  const f32x4* sp = (const f32x4*)(s + (size_t)i * 8);
  f32x4 a = sp[0], b = sp[1];
  short8 o;
  o[0] = (short)f2bf(a[0]); o[1] = (short)f2bf(a[1]);
  o[2] = (short)f2bf(a[2]); o[3] = (short)f2bf(a[3]);
  o[4] = (short)f2bf(b[0]); o[5] = (short)f2bf(b[1]);
  o[6] = (short)f2bf(b[2]); o[7] = (short)f2bf(b[3]);
  *(short8*)(d + (size_t)i * 8) = o;
}

// ---------------- GEMM: C[M x 1024] = A[M x 1024] @ BT^T + bias -------------
// 1-D grid (blocks = Mtiles*8), XCD chunk swizzle, N-fastest decomposition.
// EPI 0: bf16 out.  EPI 1: f32 out + residual + shifted store (skip j>=1985).
template <int EPI>
__launch_bounds__(256, 2)
__global__ void gemm_bt(const ushort_t* __restrict__ A, const ushort_t* __restrict__ BT,
                        const float* __restrict__ bias, ushort_t* __restrict__ Cb,
                        float* __restrict__ Cf, const float* __restrict__ resid) {
  constexpr int K = 1024;
  __shared__ __attribute__((aligned(16))) ushort_t As[128 * 32];
  __shared__ __attribute__((aligned(16))) ushort_t Bs[128 * 32];
  const int bid = blockIdx.x, cpx = gridDim.x >> 3;
  const int swz = (bid & 7) * cpx + (bid >> 3);
  const int tm = (swz >> 3) * 128, tn = (swz & 7) * 128;
  const int t = threadIdx.x, lane = t & 63, wv = t >> 6;
  const int wm = (wv >> 1) * 64, wn = (wv & 1) * 64;
  const int row = lane & 15, kg = (lane >> 4) * 8;
  f32x4 acc[4][4] = {};
  const int r0 = t >> 2, ko = (t & 3) * 8;
  const ushort_t* Ap = A + (size_t)(tm + r0) * K + ko;
  const ushort_t* Bp = BT + (size_t)(tn + r0) * K + ko;
  for (int k0 = 0; k0 < K; k0 += 32) {
    gl_lds16(Ap + k0, &As[t * 8]);
    gl_lds16(Ap + 64 * K + k0, &As[(t + 256) * 8]);
    gl_lds16(Bp + k0, &Bs[t * 8]);
    gl_lds16(Bp + 64 * K + k0, &Bs[(t + 256) * 8]);
    __syncthreads();
    short8 af[4], bfr[4];
#pragma unroll
    for (int m = 0; m < 4; m++) af[m] = *(const short8*)&As[(wm + m * 16 + row) * 32 + kg];
#pragma unroll
    for (int n = 0; n < 4; n++) bfr[n] = *(const short8*)&Bs[(wn + n * 16 + row) * 32 + kg];
#pragma unroll
    for (int m = 0; m < 4; m++)
#pragma unroll
      for (int n = 0; n < 4; n++)
        acc[m][n] = __builtin_amdgcn_mfma_f32_16x16x32_bf16(af[m], bfr[n], acc[m][n], 0, 0, 0);
    __syncthreads();
  }
  const int cr = (lane >> 4) * 4, cc = lane & 15;
#pragma unroll
  for (int m = 0; m < 4; m++) {
#pragma unroll
    for (int n = 0; n < 4; n++) {
      int col = tn + wn + n * 16 + cc;
      float bsv = bias[col];
#pragma unroll
      for (int j = 0; j < 4; j++) {
        int rg = tm + wm + m * 16 + cr + j;
        float v = acc[m][n][j] + bsv;
        if (EPI == 0) {
          Cb[(size_t)rg * 1024 + col] = f2bf(v);
        } else {
          int b = rg >> 11, jj = rg & 2047;
          if (jj < 1985) {
            size_t oi = ((size_t)(b << 11) + jj + 63) * 1024 + col;
            Cf[oi] = v + resid[oi];
          }
        }
      }
    }
  }
}

// ---------------- fused K+V projection GEMM ---------------------------------
// C_k = A @ BkT^T + bk ; C_v = A @ BvT^T + bv. A staged once per tile.
__launch_bounds__(256, 2)
__global__ void gemm_kv(const ushort_t* __restrict__ A, const ushort_t* __restrict__ BkT,
                        const ushort_t* __restrict__ BvT, const float* __restrict__ bk,
                        const float* __restrict__ bv, ushort_t* __restrict__ Ko,
                        ushort_t* __restrict__ Vo) {
  constexpr int K = 1024;
  __shared__ __attribute__((aligned(16))) ushort_t As[128 * 32];
  __shared__ __attribute__((aligned(16))) ushort_t Bks[128 * 32];
  __shared__ __attribute__((aligned(16))) ushort_t Bvs[128 * 32];
  const int bid = blockIdx.x, cpx = gridDim.x >> 3;
  const int swz = (bid & 7) * cpx + (bid >> 3);
  const int tm = (swz >> 3) * 128, tn = (swz & 7) * 128;
  const int t = threadIdx.x, lane = t & 63, wv = t >> 6;
  const int wm = (wv >> 1) * 64, wn = (wv & 1) * 64;
  const int row = lane & 15, kg = (lane >> 4) * 8;
  f32x4 ak[4][4] = {}, av[4][4] = {};
  const int r0 = t >> 2, ko = (t & 3) * 8;
  const ushort_t* Ap  = A   + (size_t)(tm + r0) * K + ko;
  const ushort_t* Bkp = BkT + (size_t)(tn + r0) * K + ko;
  const ushort_t* Bvp = BvT + (size_t)(tn + r0) * K + ko;
  for (int k0 = 0; k0 < K; k0 += 32) {
    gl_lds16(Ap + k0, &As[t * 8]);
    gl_lds16(Ap + 64 * K + k0, &As[(t + 256) * 8]);
    gl_lds16(Bkp + k0, &Bks[t * 8]);
    gl_lds16(Bkp + 64 * K + k0, &Bks[(t + 256) * 8]);
    gl_lds16(Bvp + k0, &Bvs[t * 8]);
    gl_lds16(Bvp + 64 * K + k0, &Bvs[(t + 256) * 8]);
    __syncthreads();
    short8 af[4], bkf[4], bvf[4];
#pragma unroll
    for (int m = 0; m < 4; m++) af[m] = *(const short8*)&As[(wm + m * 16 + row) * 32 + kg];
#pragma unroll
    for (int n = 0; n < 4; n++) {
      bkf[n] = *(const short8*)&Bks[(wn + n * 16 + row) * 32 + kg];
      bvf[n] = *(const short8*)&Bvs[(wn + n * 16 + row) * 32 + kg];
    }
#pragma unroll
    for (int m = 0; m < 4; m++)
#pragma unroll
      for (int n = 0; n < 4; n++) {
        ak[m][n] = __builtin_amdgcn_mfma_f32_16x16x32_bf16(af[m], bkf[n], ak[m][n], 0, 0, 0);
        av[m][n] = __builtin_amdgcn_mfma_f32_16x16x32_bf16(af[m], bvf[n], av[m][n], 0, 0, 0);
      }
    __syncthreads();
  }
  const int cr = (lane >> 4) * 4, cc = lane & 15;
#pragma unroll
  for (int m = 0; m < 4; m++) {
#pragma unroll
    for (int n = 0; n < 4; n++) {
      int col = tn + wn + n * 16 + cc;
      float bkv = bk[col], bvv = bv[col];
#pragma unroll
      for (int j = 0; j < 4; j++) {
        size_t rg = (size_t)(tm + wm + m * 16 + cr + j);
        Ko[rg * 1024 + col] = f2bf(ak[m][n][j] + bkv);
        Vo[rg * 1024 + col] = f2bf(av[m][n][j] + bvv);
      }
    }
  }
}

// ---------------- attention: one block per (b,c,h) --------------------------
// Q[64x64] @ K[256x64]^T -> softmax(256) -> @ V[256x64] -> O[64x64]
// LDS: R0 = {Qs 8K + Ks 32K} overlaid by bf16 S/P (33.75K); Vt 33.75K. 74 KB.
__launch_bounds__(256, 2)
__global__ void attn_kernel(const ushort_t* __restrict__ Q, const ushort_t* __restrict__ Kb,
                            const ushort_t* __restrict__ Vb, ushort_t* __restrict__ Ob) {
  __shared__ __attribute__((aligned(16))) ushort_t R0[20480];     // Qs[4096]+Ks[16384]
  __shared__ __attribute__((aligned(16))) ushort_t Vt[64 * 264];  // V^T, padded stride
  ushort_t* Qs = R0;
  ushort_t* Ks = R0 + 4096;
  ushort_t* Sp = R0;  // bf16 S/P [64][264] overlays Qs+Ks after QK^T

  const int hh = blockIdx.x, cch = blockIdx.y, b = blockIdx.z;
  const int t = threadIdx.x, lane = t & 63, wv = t >> 6;
  const size_t qbase = ((size_t)(b * 32 + cch) * 64) * 1024 + hh * 64;
  const size_t kvbase = ((size_t)(b * 32 + cch) * 256) * 1024 + hh * 64;

  // Q: 512 16B chunks, XOR-swizzled on 16B slot within row (row stride 128B)
  {
    int ch = t, r = ch >> 3, g = (ch & 7) ^ (r & 7);
    gl_lds16(Q + qbase + (size_t)r * 1024 + g * 8, &Qs[ch * 8]);
    ch = t + 256; r = ch >> 3; g = (ch & 7) ^ (r & 7);
    gl_lds16(Q + qbase + (size_t)r * 1024 + g * 8, &Qs[ch * 8]);
  }
  // K: 2048 chunks, same swizzle
#pragma unroll
  for (int p = 0; p < 8; p++) {
    int ch = t + 256 * p;
    int r = ch >> 3, g = (ch & 7) ^ (r & 7);
    gl_lds16(Kb + kvbase + (size_t)r * 1024 + g * 8, &Ks[ch * 8]);
  }
  // V transposed into Vt[d][j] (stride 264)
#pragma unroll
  for (int p = 0; p < 8; p++) {
    int ch = t + 256 * p;
    int j = ch >> 3, d0 = (ch & 7) * 8;
    short8 vv = *(const short8*)(Vb + kvbase + (size_t)j * 1024 + d0);
#pragma unroll
    for (int ii = 0; ii < 8; ii++) Vt[(d0 + ii) * 264 + j] = (ushort_t)vv[ii];
  }
  __syncthreads();

  const int row = lane & 15, kg = (lane >> 4) * 8;
  const int cswz = (row & 7) << 3;  // XOR term for swizzled Q/K reads
  // S = Q @ K^T ; wave wv covers kv cols [wv*64, wv*64+64)
  f32x4 accs[4][4] = {};
#pragma unroll
  for (int kk = 0; kk < 64; kk += 32) {
    int cq = ((kk + kg) ^ cswz);  // swizzled column offset (elements)
    short8 af[4], bfr[4];
#pragma unroll
    for (int m = 0; m < 4; m++) af[m] = *(const short8*)&Qs[(m * 16 + row) * 64 + cq];
#pragma unroll
    for (int n = 0; n < 4; n++)
      bfr[n] = *(const short8*)&Ks[(wv * 64 + n * 16 + row) * 64 + cq];
#pragma unroll
    for (int m = 0; m < 4; m++)
#pragma unroll
      for (int n = 0; n < 4; n++)
        accs[m][n] = __builtin_amdgcn_mfma_f32_16x16x32_bf16(af[m], bfr[n], accs[m][n], 0, 0, 0);
  }
  __syncthreads();  // Qs/Ks reads complete -> safe to overlay with S

  {
    const int cr = (lane >> 4) * 4, cc = lane & 15;
#pragma unroll
    for (int m = 0; m < 4; m++)
#pragma unroll
      for (int n = 0; n < 4; n++)
#pragma unroll
        for (int j = 0; j < 4; j++)
          Sp[(m * 16 + cr + j) * 264 + wv * 64 + n * 16 + cc] = f2bf(accs[m][n][j]);
  }
  __syncthreads();

  // softmax over 256: 4 threads/row, thread q handles contiguous cols [q*64,q*64+64)
  {
    const int r = t >> 2, q = t & 3;
    const int base = r * 264 + q * 64;
    float ev[64];
#pragma unroll
    for (int p = 0; p < 8; p++) {
      short8 sv = *(const short8*)&Sp[base + p * 8];
#pragma unroll
      for (int i = 0; i < 8; i++) ev[p * 8 + i] = bf2f((ushort_t)sv[i]);
    }
    float mx = ev[0];
#pragma unroll
    for (int i = 1; i < 64; i++) mx = fmaxf(mx, ev[i]);
    mx = fmaxf(mx, __shfl_xor(mx, 1));
    mx = fmaxf(mx, __shfl_xor(mx, 2));
    float sum = 0.f;
#pragma unroll
    for (int i = 0; i < 64; i++) {
      ev[i] = __expf((ev[i] - mx) * 0.125f);
      sum += ev[i];
    }
    sum += __shfl_xor(sum, 1);
    sum += __shfl_xor(sum, 2);
    float inv = 1.f / sum;
    // write P in place (each thread rewrites exactly the cols it read)
#pragma unroll
    for (int p = 0; p < 8; p++) {
      short8 pv;
#pragma unroll
      for (int i = 0; i < 8; i++) pv[i] = (short)f2bf(ev[p * 8 + i] * inv);
      *(short8*)&Sp[base + p * 8] = pv;
    }
  }
  __syncthreads();

  // O = P @ V ; wave wv covers d cols [wv*16, wv*16+16)
  {
    f32x4 acco[4] = {};
#pragma unroll
    for (int kt = 0; kt < 8; kt++) {
      short8 bfv = *(const short8*)&Vt[(wv * 16 + row) * 264 + kt * 32 + kg];
#pragma unroll
      for (int m = 0; m < 4; m++) {
        short8 af = *(const short8*)&Sp[(m * 16 + row) * 264 + kt * 32 + kg];
        acco[m] = __builtin_amdgcn_mfma_f32_16x16x32_bf16(af, bfv, acco[m], 0, 0, 0);
      }
    }
    const int cr = (lane >> 4) * 4, cc = lane & 15;
    size_t obase = ((size_t)(b * 32 + cch) * 64) * 1024 + hh * 64 + wv * 16 + cc;
#pragma unroll
    for (int m = 0; m < 4; m++)
#pragma unroll
      for (int j = 0; j < 4; j++)
        Ob[obase + (size_t)(m * 16 + cr + j) * 1024] = f2bf(acco[m][j]);
  }
}

// ---------------- residual-only prologue rows t < 63 ------------------------
__global__ void copy_prologue(const float* __restrict__ h, float* __restrict__ out) {
  int tt = blockIdx.x;  // 0..251
  int b = tt / 63, r = tt % 63;
  size_t idx = ((size_t)(b * 2048) + r) * 1024 + threadIdx.x * 4;
  *(f32x4*)&out[idx] = *(const f32x4*)&h[idx];
}

extern "C" void kernel_launch(void* const* d_in, const int* in_sizes, int n_in,
                              void* d_out, int out_size, void* d_ws, size_t ws_size,
                              hipStream_t stream) {
  const float* h    = (const float*)d_in[0];
  const float* e    = (const float*)d_in[1];
  const float* ln_g = (const float*)d_in[2];
  const float* ln_b = (const float*)d_in[3];
  const float* Wq   = (const float*)d_in[4];
  const float* bq   = (const float*)d_in[5];
  const float* Wk   = (const float*)d_in[6];
  const float* bk   = (const float*)d_in[7];
  const float* Wv   = (const float*)d_in[8];
  const float* bv   = (const float*)d_in[9];
  const float* Wo   = (const float*)d_in[10];
  const float* bo   = (const float*)d_in[11];
  float* out = (float*)d_out;

  char* ws = (char*)d_ws;
  const size_t MB = 1024 * 1024;
  ushort_t* WqT  = (ushort_t*)(ws + 0 * MB);
  ushort_t* WkT  = (ushort_t*)(ws + 2 * MB);
  ushort_t* WvT  = (ushort_t*)(ws + 4 * MB);
  ushort_t* WoT  = (ushort_t*)(ws + 6 * MB);
  ushort_t* hb   = (ushort_t*)(ws + 8 * MB);    // 16 MB
  ushort_t* e_bf = (ushort_t*)(ws + 24 * MB);   // 64 MB
  ushort_t* Qb   = (ushort_t*)(ws + 88 * MB);   // 16 MB
  ushort_t* Kbuf = (ushort_t*)(ws + 104 * MB);  // 64 MB
  ushort_t* Vbuf = (ushort_t*)(ws + 168 * MB);  // 64 MB
  ushort_t* Obuf = (ushort_t*)(ws + 232 * MB);  // 16 MB -> total 248 MB

  dim3 g32(32, 32);
  transpose_w<<<g32, 256, 0, stream>>>(Wq, WqT);
  transpose_w<<<g32, 256, 0, stream>>>(Wk, WkT);
  transpose_w<<<g32, 256, 0, stream>>>(Wv, WvT);
  transpose_w<<<g32, 256, 0, stream>>>(Wo, WoT);

  ln_kernel<<<8192, 256, 0, stream>>>(h, ln_g, ln_b, hb);
  conv_bf16<<<16384, 256, 0, stream>>>(e, e_bf, 4194304);  // 32768*1024/8

  gemm_bt<0><<<512, 256, 0, stream>>>(hb, WqT, bq, Qb, nullptr, nullptr);
  gemm_kv<<<2048, 256, 0, stream>>>(e_bf, WkT, WvT, bk, bv, Kbuf, Vbuf);

  attn_kernel<<<dim3(16, 32, 4), 256, 0, stream>>>(Qb, Kbuf, Vbuf, Obuf);

  gemm_bt<1><<<512, 256, 0, stream>>>(Obuf, WoT, bo, nullptr, out, h);
  copy_prologue<<<252, 256, 0, stream>>>(h, out);
}

// Round 3
// 342.299 us; speedup vs baseline: 1.1343x; 1.0628x over previous
//
#include <hip/hip_runtime.h>

// RETRO chunked cross-attention, MI355X bf16 MFMA pipeline. Round 3:
//  - KV projection as one 256x256-tile 8-phase-style GEMM (N=2048, concat Wk|Wv),
//    4-deep K-tile LDS ring (BK=32), counted vmcnt(4), raw s_barrier, setprio,
//    XOR-swizzled LDS (both-sides involution per rule 21).
//  - Q/O GEMMs, attention, elementwise stages unchanged from round 2.

typedef __attribute__((ext_vector_type(8))) short short8;
typedef __attribute__((ext_vector_type(4))) float f32x4;
typedef unsigned short ushort_t;

__device__ inline ushort_t f2bf(float f) {
  union { float f; unsigned int u; } v; v.f = f;
  unsigned int u = v.u;
  return (ushort_t)((u + 0x7fffu + ((u >> 16) & 1u)) >> 16);
}
__device__ inline float bf2f(ushort_t s) {
  union { unsigned int u; float f; } v; v.u = ((unsigned int)s) << 16;
  return v.f;
}

__device__ inline void gl_lds16(const void* g, void* l) {
  __builtin_amdgcn_global_load_lds(
      (const __attribute__((address_space(1))) unsigned int*)g,
      (__attribute__((address_space(3))) unsigned int*)l, 16, 0, 0);
}

// ---------------- weight transpose + bf16 cast: WT[n][k] = W[k][n] ----------
__global__ void transpose_w(const float* __restrict__ W, ushort_t* __restrict__ WT) {
  __shared__ float tile[32][33];
  int k0 = blockIdx.x * 32, n0 = blockIdx.y * 32;
  int c = threadIdx.x & 31, r = threadIdx.x >> 5;  // r in 0..7
#pragma unroll
  for (int p = 0; p < 4; p++)
    tile[r + p * 8][c] = W[(size_t)(k0 + r + p * 8) * 1024 + n0 + c];
  __syncthreads();
#pragma unroll
  for (int p = 0; p < 4; p++)
    WT[(size_t)(n0 + r + p * 8) * 1024 + k0 + c] = f2bf(tile[c][r + p * 8]);
}

// ---------------- shifted LayerNorm -> bf16 query rows ----------------------
__global__ void ln_kernel(const float* __restrict__ h, const float* __restrict__ g,
                          const float* __restrict__ bb, ushort_t* __restrict__ hb) {
  int row = blockIdx.x;            // 0..8191
  int b = row >> 11, jj = row & 2047;
  int t = threadIdx.x;
  ushort_t* dst = hb + (size_t)row * 1024;
  if (jj >= 1985) {
    ((unsigned int*)dst)[t] = 0u;
    ((unsigned int*)dst)[t + 256] = 0u;
    return;
  }
  const float* src = h + ((size_t)(b << 11) + jj + 63) * 1024;
  f32x4 x = *(const f32x4*)&src[t * 4];
  float s = x[0] + x[1] + x[2] + x[3];
  float sq = x[0]*x[0] + x[1]*x[1] + x[2]*x[2] + x[3]*x[3];
#pragma unroll
  for (int off = 32; off > 0; off >>= 1) {
    s  += __shfl_xor(s, off);
    sq += __shfl_xor(sq, off);
  }
  __shared__ float red[8];
  if ((t & 63) == 0) { red[(t >> 6) * 2] = s; red[(t >> 6) * 2 + 1] = sq; }
  __syncthreads();
  float sum = red[0] + red[2] + red[4] + red[6];
  float sumsq = red[1] + red[3] + red[5] + red[7];
  float mu = sum * (1.f / 1024.f);
  float var = sumsq * (1.f / 1024.f) - mu * mu;
  float rs = rsqrtf(var + 1e-5f);
  f32x4 gg = *(const f32x4*)&g[t * 4];
  f32x4 bv = *(const f32x4*)&bb[t * 4];
  ushort_t o0 = f2bf((x[0] - mu) * rs * gg[0] + bv[0]);
  ushort_t o1 = f2bf((x[1] - mu) * rs * gg[1] + bv[1]);
  ushort_t o2 = f2bf((x[2] - mu) * rs * gg[2] + bv[2]);
  ushort_t o3 = f2bf((x[3] - mu) * rs * gg[3] + bv[3]);
  unsigned long long pack = (unsigned long long)o0 | ((unsigned long long)o1 << 16)
                          | ((unsigned long long)o2 << 32) | ((unsigned long long)o3 << 48);
  *(unsigned long long*)&dst[t * 4] = pack;
}

// ---------------- f32 -> bf16 cast (vector) ---------------------------------
__global__ void conv_bf16(const float* __restrict__ s, ushort_t* __restrict__ d, int n8) {
  int i = blockIdx.x * 256 + threadIdx.x;
  if (i >= n8) return;
  const f32x4* sp = (const f32x4*)(s + (size_t)i * 8);
  f32x4 a = sp[0], b = sp[1];
  short8 o;
  o[0] = (short)f2bf(a[0]); o[1] = (short)f2bf(a[1]);
  o[2] = (short)f2bf(a[2]); o[3] = (short)f2bf(a[3]);
  o[4] = (short)f2bf(b[0]); o[5] = (short)f2bf(b[1]);
  o[6] = (short)f2bf(b[2]); o[7] = (short)f2bf(b[3]);
  *(short8*)(d + (size_t)i * 8) = o;
}

// ---------------- GEMM: C[M x 1024] = A[M x 1024] @ BT^T + bias -------------
// 1-D grid (blocks = Mtiles*8), XCD chunk swizzle, N-fastest decomposition.
template <int EPI>
__launch_bounds__(256, 2)
__global__ void gemm_bt(const ushort_t* __restrict__ A, const ushort_t* __restrict__ BT,
                        const float* __restrict__ bias, ushort_t* __restrict__ Cb,
                        float* __restrict__ Cf, const float* __restrict__ resid) {
  constexpr int K = 1024;
  __shared__ __attribute__((aligned(16))) ushort_t As[128 * 32];
  __shared__ __attribute__((aligned(16))) ushort_t Bs[128 * 32];
  const int bid = blockIdx.x, cpx = gridDim.x >> 3;
  const int swz = (bid & 7) * cpx + (bid >> 3);
  const int tm = (swz >> 3) * 128, tn = (swz & 7) * 128;
  const int t = threadIdx.x, lane = t & 63, wv = t >> 6;
  const int wm = (wv >> 1) * 64, wn = (wv & 1) * 64;
  const int row = lane & 15, kg = (lane >> 4) * 8;
  f32x4 acc[4][4] = {};
  const int r0 = t >> 2, ko = (t & 3) * 8;
  const ushort_t* Ap = A + (size_t)(tm + r0) * K + ko;
  const ushort_t* Bp = BT + (size_t)(tn + r0) * K + ko;
  for (int k0 = 0; k0 < K; k0 += 32) {
    gl_lds16(Ap + k0, &As[t * 8]);
    gl_lds16(Ap + 64 * K + k0, &As[(t + 256) * 8]);
    gl_lds16(Bp + k0, &Bs[t * 8]);
    gl_lds16(Bp + 64 * K + k0, &Bs[(t + 256) * 8]);
    __syncthreads();
    short8 af[4], bfr[4];
#pragma unroll
    for (int m = 0; m < 4; m++) af[m] = *(const short8*)&As[(wm + m * 16 + row) * 32 + kg];
#pragma unroll
    for (int n = 0; n < 4; n++) bfr[n] = *(const short8*)&Bs[(wn + n * 16 + row) * 32 + kg];
#pragma unroll
    for (int m = 0; m < 4; m++)
#pragma unroll
      for (int n = 0; n < 4; n++)
        acc[m][n] = __builtin_amdgcn_mfma_f32_16x16x32_bf16(af[m], bfr[n], acc[m][n], 0, 0, 0);
    __syncthreads();
  }
  const int cr = (lane >> 4) * 4, cc = lane & 15;
#pragma unroll
  for (int m = 0; m < 4; m++) {
#pragma unroll
    for (int n = 0; n < 4; n++) {
      int col = tn + wn + n * 16 + cc;
      float bsv = bias[col];
#pragma unroll
      for (int j = 0; j < 4; j++) {
        int rg = tm + wm + m * 16 + cr + j;
        float v = acc[m][n][j] + bsv;
        if (EPI == 0) {
          Cb[(size_t)rg * 1024 + col] = f2bf(v);
        } else {
          int b = rg >> 11, jj = rg & 2047;
          if (jj < 1985) {
            size_t oi = ((size_t)(b << 11) + jj + 63) * 1024 + col;
            Cf[oi] = v + resid[oi];
          }
        }
      }
    }
  }
}

// ---------------- KV projection: 256x256 tile, 8-phase-style schedule -------
// C[32768 x 2048] = A @ [WkT|WvT]^T, split-written to Ko / Vo.
// 8 waves (2M x 4N), BK=32, 4-buffer LDS ring (128 KB), counted vmcnt(4).
__launch_bounds__(512, 2)
__global__ void gemm_kv256(const ushort_t* __restrict__ A, const ushort_t* __restrict__ BT,
                           const float* __restrict__ bk, const float* __restrict__ bv,
                           ushort_t* __restrict__ Ko, ushort_t* __restrict__ Vo) {
  __shared__ __attribute__((aligned(16))) ushort_t lds[65536];  // 4 x (A 16KB + B 16KB)
  const int bid = blockIdx.x;                    // 1024 blocks, %8==0 -> bijective swizzle
  const int swz = (bid & 7) * 128 + (bid >> 3);  // XCD chunk swizzle
  const int tm = (swz >> 3) * 256, tn = (swz & 7) * 256;
  const int t = threadIdx.x, lane = t & 63, wv = t >> 6;
  const int wm = wv >> 2, wn = wv & 3;           // 2M x 4N wave grid
  const int row16 = lane & 15, g = lane >> 4;

  // staging geometry: per tile, A region = 1024 16B chunks, thread does chunks t, t+512.
  // LDS dest linear; global source pre-swizzled by the same XOR involution
  // (byte ^= ((byte>>7)&3)<<4  ==  slot ^= (row>>1)&3).
  const int d1 = t + 512;
  const int ra0 = t >> 2, sa0 = ((t & 3) ^ ((ra0 >> 1) & 3)) * 8;
  const int ra1 = d1 >> 2, sa1 = ((d1 & 3) ^ ((ra1 >> 1) & 3)) * 8;
  const ushort_t* Ag0 = A + (size_t)(tm + ra0) * 1024 + sa0;
  const ushort_t* Ag1 = A + (size_t)(tm + ra1) * 1024 + sa1;
  const ushort_t* Bg0 = BT + (size_t)(tn + ra0) * 1024 + sa0;
  const ushort_t* Bg1 = BT + (size_t)(tn + ra1) * 1024 + sa1;

#define STAGE_A(T) { ushort_t* Ab_ = lds + ((T) & 3) * 16384; const int k0_ = (T) * 32; \
    gl_lds16(Ag0 + k0_, Ab_ + t * 8); gl_lds16(Ag1 + k0_, Ab_ + d1 * 8); }
#define STAGE_B(T) { ushort_t* Bb_ = lds + ((T) & 3) * 16384 + 8192; const int k0_ = (T) * 32; \
    gl_lds16(Bg0 + k0_, Bb_ + t * 8); gl_lds16(Bg1 + k0_, Bb_ + d1 * 8); }

  // swizzled fragment read offsets (elements)
  int aoff[8], boff[4];
#pragma unroll
  for (int m = 0; m < 8; m++) {
    int ra = wm * 128 + m * 16 + row16;
    aoff[m] = ra * 32 + (g ^ ((ra >> 1) & 3)) * 8;
  }
#pragma unroll
  for (int n = 0; n < 4; n++) {
    int rb = wn * 64 + n * 16 + row16;
    boff[n] = rb * 32 + (g ^ ((rb >> 1) & 3)) * 8;
  }

  f32x4 acc[8][4] = {};
  STAGE_A(0); STAGE_B(0); STAGE_A(1); STAGE_B(1);

  for (int T = 0; T < 32; ++T) {
    const ushort_t* Ab = lds + (T & 3) * 16384;
    const ushort_t* Bb = Ab + 8192;
    if (T < 31) { asm volatile("s_waitcnt vmcnt(4)" ::: "memory"); }
    else        { asm volatile("s_waitcnt vmcnt(0)" ::: "memory"); }
    __builtin_amdgcn_s_barrier();

    short8 af[4], bfv[4];
    // ---- phase 0: m-frags 0..3, all B-frags ----
#pragma unroll
    for (int m = 0; m < 4; m++) af[m] = *(const short8*)&Ab[aoff[m]];
#pragma unroll
    for (int n = 0; n < 4; n++) bfv[n] = *(const short8*)&Bb[boff[n]];
    if (T < 30) STAGE_A(T + 2);
    __builtin_amdgcn_s_barrier();
    asm volatile("s_waitcnt lgkmcnt(0)" ::: "memory");
    __builtin_amdgcn_sched_barrier(0);
    __builtin_amdgcn_s_setprio(1);
#pragma unroll
    for (int m = 0; m < 4; m++)
#pragma unroll
      for (int n = 0; n < 4; n++)
        acc[m][n] = __builtin_amdgcn_mfma_f32_16x16x32_bf16(af[m], bfv[n], acc[m][n], 0, 0, 0);
    __builtin_amdgcn_s_setprio(0);
    __builtin_amdgcn_s_barrier();

    // ---- phase 1: m-frags 4..7, reuse B-frags ----
#pragma unroll
    for (int m = 0; m < 4; m++) af[m] = *(const short8*)&Ab[aoff[4 + m]];
    if (T < 30) STAGE_B(T + 2);
    __builtin_amdgcn_s_barrier();
    asm volatile("s_waitcnt lgkmcnt(0)" ::: "memory");
    __builtin_amdgcn_sched_barrier(0);
    __builtin_amdgcn_s_setprio(1);
#pragma unroll
    for (int m = 0; m < 4; m++)
#pragma unroll
      for (int n = 0; n < 4; n++)
        acc[4 + m][n] = __builtin_amdgcn_mfma_f32_16x16x32_bf16(af[m], bfv[n], acc[4 + m][n], 0, 0, 0);
    __builtin_amdgcn_s_setprio(0);
    // no barrier here: next-iter top vmcnt+barrier is the boundary
  }
#undef STAGE_A
#undef STAGE_B

  const bool isV = (tn >= 1024);
  const float* bias = isV ? bv : bk;
  ushort_t* Out = isV ? Vo : Ko;
  const int cbase = (isV ? tn - 1024 : tn) + wn * 64;
#pragma unroll
  for (int m = 0; m < 8; m++) {
    int rg = tm + wm * 128 + m * 16 + g * 4;
#pragma unroll
    for (int n = 0; n < 4; n++) {
      int col = cbase + n * 16 + row16;
      float bsv = bias[col];
#pragma unroll
      for (int j = 0; j < 4; j++)
        Out[(size_t)(rg + j) * 1024 + col] = f2bf(acc[m][n][j] + bsv);
    }
  }
}

// ---------------- attention: one block per (b,c,h) --------------------------
__launch_bounds__(256, 2)
__global__ void attn_kernel(const ushort_t* __restrict__ Q, const ushort_t* __restrict__ Kb,
                            const ushort_t* __restrict__ Vb, ushort_t* __restrict__ Ob) {
  __shared__ __attribute__((aligned(16))) ushort_t R0[20480];     // Qs[4096]+Ks[16384]
  __shared__ __attribute__((aligned(16))) ushort_t Vt[64 * 264];  // V^T, padded stride
  ushort_t* Qs = R0;
  ushort_t* Ks = R0 + 4096;
  ushort_t* Sp = R0;  // bf16 S/P [64][264] overlays Qs+Ks after QK^T

  const int hh = blockIdx.x, cch = blockIdx.y, b = blockIdx.z;
  const int t = threadIdx.x, lane = t & 63, wv = t >> 6;
  const size_t qbase = ((size_t)(b * 32 + cch) * 64) * 1024 + hh * 64;
  const size_t kvbase = ((size_t)(b * 32 + cch) * 256) * 1024 + hh * 64;

  {
    int ch = t, r = ch >> 3, g = (ch & 7) ^ (r & 7);
    gl_lds16(Q + qbase + (size_t)r * 1024 + g * 8, &Qs[ch * 8]);
    ch = t + 256; r = ch >> 3; g = (ch & 7) ^ (r & 7);
    gl_lds16(Q + qbase + (size_t)r * 1024 + g * 8, &Qs[ch * 8]);
  }
#pragma unroll
  for (int p = 0; p < 8; p++) {
    int ch = t + 256 * p;
    int r = ch >> 3, g = (ch & 7) ^ (r & 7);
    gl_lds16(Kb + kvbase + (size_t)r * 1024 + g * 8, &Ks[ch * 8]);
  }
#pragma unroll
  for (int p = 0; p < 8; p++) {
    int ch = t + 256 * p;
    int j = ch >> 3, d0 = (ch & 7) * 8;
    short8 vv = *(const short8*)(Vb + kvbase + (size_t)j * 1024 + d0);
#pragma unroll
    for (int ii = 0; ii < 8; ii++) Vt[(d0 + ii) * 264 + j] = (ushort_t)vv[ii];
  }
  __syncthreads();

  const int row = lane & 15, kg = (lane >> 4) * 8;
  const int cswz = (row & 7) << 3;
  f32x4 accs[4][4] = {};
#pragma unroll
  for (int kk = 0; kk < 64; kk += 32) {
    int cq = ((kk + kg) ^ cswz);
    short8 af[4], bfr[4];
#pragma unroll
    for (int m = 0; m < 4; m++) af[m] = *(const short8*)&Qs[(m * 16 + row) * 64 + cq];
#pragma unroll
    for (int n = 0; n < 4; n++)
      bfr[n] = *(const short8*)&Ks[(wv * 64 + n * 16 + row) * 64 + cq];
#pragma unroll
    for (int m = 0; m < 4; m++)
#pragma unroll
      for (int n = 0; n < 4; n++)
        accs[m][n] = __builtin_amdgcn_mfma_f32_16x16x32_bf16(af[m], bfr[n], accs[m][n], 0, 0, 0);
  }
  __syncthreads();

  {
    const int cr = (lane >> 4) * 4, cc = lane & 15;
#pragma unroll
    for (int m = 0; m < 4; m++)
#pragma unroll
      for (int n = 0; n < 4; n++)
#pragma unroll
        for (int j = 0; j < 4; j++)
          Sp[(m * 16 + cr + j) * 264 + wv * 64 + n * 16 + cc] = f2bf(accs[m][n][j]);
  }
  __syncthreads();

  {
    const int r = t >> 2, q = t & 3;
    const int base = r * 264 + q * 64;
    float ev[64];
#pragma unroll
    for (int p = 0; p < 8; p++) {
      short8 sv = *(const short8*)&Sp[base + p * 8];
#pragma unroll
      for (int i = 0; i < 8; i++) ev[p * 8 + i] = bf2f((ushort_t)sv[i]);
    }
    float mx = ev[0];
#pragma unroll
    for (int i = 1; i < 64; i++) mx = fmaxf(mx, ev[i]);
    mx = fmaxf(mx, __shfl_xor(mx, 1));
    mx = fmaxf(mx, __shfl_xor(mx, 2));
    float sum = 0.f;
#pragma unroll
    for (int i = 0; i < 64; i++) {
      ev[i] = __expf((ev[i] - mx) * 0.125f);
      sum += ev[i];
    }
    sum += __shfl_xor(sum, 1);
    sum += __shfl_xor(sum, 2);
    float inv = 1.f / sum;
#pragma unroll
    for (int p = 0; p < 8; p++) {
      short8 pv;
#pragma unroll
      for (int i = 0; i < 8; i++) pv[i] = (short)f2bf(ev[p * 8 + i] * inv);
      *(short8*)&Sp[base + p * 8] = pv;
    }
  }
  __syncthreads();

  {
    f32x4 acco[4] = {};
#pragma unroll
    for (int kt = 0; kt < 8; kt++) {
      short8 bfv = *(const short8*)&Vt[(wv * 16 + row) * 264 + kt * 32 + kg];
#pragma unroll
      for (int m = 0; m < 4; m++) {
        short8 af = *(const short8*)&Sp[(m * 16 + row) * 264 + kt * 32 + kg];
        acco[m] = __builtin_amdgcn_mfma_f32_16x16x32_bf16(af, bfv, acco[m], 0, 0, 0);
      }
    }
    const int cr = (lane >> 4) * 4, cc = lane & 15;
    size_t obase = ((size_t)(b * 32 + cch) * 64) * 1024 + hh * 64 + wv * 16 + cc;
#pragma unroll
    for (int m = 0; m < 4; m++)
#pragma unroll
      for (int j = 0; j < 4; j++)
        Ob[obase + (size_t)(m * 16 + cr + j) * 1024] = f2bf(acco[m][j]);
  }
}

// ---------------- residual-only prologue rows t < 63 ------------------------
__global__ void copy_prologue(const float* __restrict__ h, float* __restrict__ out) {
  int tt = blockIdx.x;  // 0..251
  int b = tt / 63, r = tt % 63;
  size_t idx = ((size_t)(b * 2048) + r) * 1024 + threadIdx.x * 4;
  *(f32x4*)&out[idx] = *(const f32x4*)&h[idx];
}

extern "C" void kernel_launch(void* const* d_in, const int* in_sizes, int n_in,
                              void* d_out, int out_size, void* d_ws, size_t ws_size,
                              hipStream_t stream) {
  const float* h    = (const float*)d_in[0];
  const float* e    = (const float*)d_in[1];
  const float* ln_g = (const float*)d_in[2];
  const float* ln_b = (const float*)d_in[3];
  const float* Wq   = (const float*)d_in[4];
  const float* bq   = (const float*)d_in[5];
  const float* Wk   = (const float*)d_in[6];
  const float* bk   = (const float*)d_in[7];
  const float* Wv   = (const float*)d_in[8];
  const float* bv   = (const float*)d_in[9];
  const float* Wo   = (const float*)d_in[10];
  const float* bo   = (const float*)d_in[11];
  float* out = (float*)d_out;

  char* ws = (char*)d_ws;
  const size_t MB = 1024 * 1024;
  ushort_t* WqT  = (ushort_t*)(ws + 0 * MB);
  ushort_t* WkT  = (ushort_t*)(ws + 2 * MB);   // WkT || WvT contiguous = BT[2048][1024]
  ushort_t* WvT  = (ushort_t*)(ws + 4 * MB);
  ushort_t* WoT  = (ushort_t*)(ws + 6 * MB);
  ushort_t* hb   = (ushort_t*)(ws + 8 * MB);    // 16 MB
  ushort_t* e_bf = (ushort_t*)(ws + 24 * MB);   // 64 MB
  ushort_t* Qb   = (ushort_t*)(ws + 88 * MB);   // 16 MB
  ushort_t* Kbuf = (ushort_t*)(ws + 104 * MB);  // 64 MB
  ushort_t* Vbuf = (ushort_t*)(ws + 168 * MB);  // 64 MB
  ushort_t* Obuf = (ushort_t*)(ws + 232 * MB);  // 16 MB -> total 248 MB

  dim3 g32(32, 32);
  transpose_w<<<g32, 256, 0, stream>>>(Wq, WqT);
  transpose_w<<<g32, 256, 0, stream>>>(Wk, WkT);
  transpose_w<<<g32, 256, 0, stream>>>(Wv, WvT);
  transpose_w<<<g32, 256, 0, stream>>>(Wo, WoT);

  ln_kernel<<<8192, 256, 0, stream>>>(h, ln_g, ln_b, hb);
  conv_bf16<<<16384, 256, 0, stream>>>(e, e_bf, 4194304);  // 32768*1024/8

  gemm_bt<0><<<512, 256, 0, stream>>>(hb, WqT, bq, Qb, nullptr, nullptr);
  gemm_kv256<<<1024, 512, 0, stream>>>(e_bf, WkT, bk, bv, Kbuf, Vbuf);

  attn_kernel<<<dim3(16, 32, 4), 256, 0, stream>>>(Qb, Kbuf, Vbuf, Obuf);

  gemm_bt<1><<<512, 256, 0, stream>>>(Obuf, WoT, bo, nullptr, out, h);
  copy_prologue<<<252, 256, 0, stream>>>(h, out);
}

// Round 4
// 328.068 us; speedup vs baseline: 1.1835x; 1.0434x over previous
//
#include <hip/hip_runtime.h>

// RETRO chunked cross-attention, MI355X bf16 MFMA pipeline. Round 4:
//  - pi column-permutation (within each 64-col head group) applied at store
//    time to Q, K, V: epilogue stores become 8B-packed coalesced (128->32
//    stores/thread in kv GEMM). QK^T invariant (both sides permuted); attn
//    V-transpose applies pi^-1 so PV/O stay natural.
//  - kv GEMM: drop explicit lgkmcnt(0)/sched_barrier before MFMA clusters;
//    compiler emits fine-grained per-frag waits (waves stagger MFMA vs LDS).

typedef __attribute__((ext_vector_type(8))) short short8;
typedef __attribute__((ext_vector_type(4))) float f32x4;
typedef unsigned short ushort_t;
typedef unsigned long long u64;

__device__ inline ushort_t f2bf(float f) {
  union { float f; unsigned int u; } v; v.f = f;
  unsigned int u = v.u;
  return (ushort_t)((u + 0x7fffu + ((u >> 16) & 1u)) >> 16);
}
__device__ inline float bf2f(ushort_t s) {
  union { unsigned int u; float f; } v; v.u = ((unsigned int)s) << 16;
  return v.f;
}

__device__ inline void gl_lds16(const void* g, void* l) {
  __builtin_amdgcn_global_load_lds(
      (const __attribute__((address_space(1))) unsigned int*)g,
      (__attribute__((address_space(3))) unsigned int*)l, 16, 0, 0);
}

// ---------------- weight transpose + bf16 cast: WT[n][k] = W[k][n] ----------
__global__ void transpose_w(const float* __restrict__ W, ushort_t* __restrict__ WT) {
  __shared__ float tile[32][33];
  int k0 = blockIdx.x * 32, n0 = blockIdx.y * 32;
  int c = threadIdx.x & 31, r = threadIdx.x >> 5;  // r in 0..7
#pragma unroll
  for (int p = 0; p < 4; p++)
    tile[r + p * 8][c] = W[(size_t)(k0 + r + p * 8) * 1024 + n0 + c];
  __syncthreads();
#pragma unroll
  for (int p = 0; p < 4; p++)
    WT[(size_t)(n0 + r + p * 8) * 1024 + k0 + c] = f2bf(tile[c][r + p * 8]);
}

// ---------------- shifted LayerNorm -> bf16 query rows ----------------------
__global__ void ln_kernel(const float* __restrict__ h, const float* __restrict__ g,
                          const float* __restrict__ bb, ushort_t* __restrict__ hb) {
  int row = blockIdx.x;            // 0..8191
  int b = row >> 11, jj = row & 2047;
  int t = threadIdx.x;
  ushort_t* dst = hb + (size_t)row * 1024;
  if (jj >= 1985) {
    ((unsigned int*)dst)[t] = 0u;
    ((unsigned int*)dst)[t + 256] = 0u;
    return;
  }
  const float* src = h + ((size_t)(b << 11) + jj + 63) * 1024;
  f32x4 x = *(const f32x4*)&src[t * 4];
  float s = x[0] + x[1] + x[2] + x[3];
  float sq = x[0]*x[0] + x[1]*x[1] + x[2]*x[2] + x[3]*x[3];
#pragma unroll
  for (int off = 32; off > 0; off >>= 1) {
    s  += __shfl_xor(s, off);
    sq += __shfl_xor(sq, off);
  }
  __shared__ float red[8];
  if ((t & 63) == 0) { red[(t >> 6) * 2] = s; red[(t >> 6) * 2 + 1] = sq; }
  __syncthreads();
  float sum = red[0] + red[2] + red[4] + red[6];
  float sumsq = red[1] + red[3] + red[5] + red[7];
  float mu = sum * (1.f / 1024.f);
  float var = sumsq * (1.f / 1024.f) - mu * mu;
  float rs = rsqrtf(var + 1e-5f);
  f32x4 gg = *(const f32x4*)&g[t * 4];
  f32x4 bv = *(const f32x4*)&bb[t * 4];
  ushort_t o0 = f2bf((x[0] - mu) * rs * gg[0] + bv[0]);
  ushort_t o1 = f2bf((x[1] - mu) * rs * gg[1] + bv[1]);
  ushort_t o2 = f2bf((x[2] - mu) * rs * gg[2] + bv[2]);
  ushort_t o3 = f2bf((x[3] - mu) * rs * gg[3] + bv[3]);
  u64 pack = (u64)o0 | ((u64)o1 << 16) | ((u64)o2 << 32) | ((u64)o3 << 48);
  *(u64*)&dst[t * 4] = pack;
}

// ---------------- f32 -> bf16 cast (vector) ---------------------------------
__global__ void conv_bf16(const float* __restrict__ s, ushort_t* __restrict__ d, int n8) {
  int i = blockIdx.x * 256 + threadIdx.x;
  if (i >= n8) return;
  const f32x4* sp = (const f32x4*)(s + (size_t)i * 8);
  f32x4 a = sp[0], b = sp[1];
  short8 o;
  o[0] = (short)f2bf(a[0]); o[1] = (short)f2bf(a[1]);
  o[2] = (short)f2bf(a[2]); o[3] = (short)f2bf(a[3]);
  o[4] = (short)f2bf(b[0]); o[5] = (short)f2bf(b[1]);
  o[6] = (short)f2bf(b[2]); o[7] = (short)f2bf(b[3]);
  *(short8*)(d + (size_t)i * 8) = o;
}

// ---------------- GEMM: C[M x 1024] = A[M x 1024] @ BT^T + bias -------------
// EPI 0: bf16 out with pi column-permutation, 8B packed stores (Q path).
// EPI 1: f32 out + residual + shifted store, natural columns (O path).
template <int EPI>
__launch_bounds__(256, 2)
__global__ void gemm_bt(const ushort_t* __restrict__ A, const ushort_t* __restrict__ BT,
                        const float* __restrict__ bias, ushort_t* __restrict__ Cb,
                        float* __restrict__ Cf, const float* __restrict__ resid) {
  constexpr int K = 1024;
  __shared__ __attribute__((aligned(16))) ushort_t As[128 * 32];
  __shared__ __attribute__((aligned(16))) ushort_t Bs[128 * 32];
  const int bid = blockIdx.x, cpx = gridDim.x >> 3;
  const int swz = (bid & 7) * cpx + (bid >> 3);
  const int tm = (swz >> 3) * 128, tn = (swz & 7) * 128;
  const int t = threadIdx.x, lane = t & 63, wv = t >> 6;
  const int wm = (wv >> 1) * 64, wn = (wv & 1) * 64;
  const int row = lane & 15, kg = (lane >> 4) * 8;
  f32x4 acc[4][4] = {};
  const int r0 = t >> 2, ko = (t & 3) * 8;
  const ushort_t* Ap = A + (size_t)(tm + r0) * K + ko;
  const ushort_t* Bp = BT + (size_t)(tn + r0) * K + ko;
  for (int k0 = 0; k0 < K; k0 += 32) {
    gl_lds16(Ap + k0, &As[t * 8]);
    gl_lds16(Ap + 64 * K + k0, &As[(t + 256) * 8]);
    gl_lds16(Bp + k0, &Bs[t * 8]);
    gl_lds16(Bp + 64 * K + k0, &Bs[(t + 256) * 8]);
    __syncthreads();
    short8 af[4], bfr[4];
#pragma unroll
    for (int m = 0; m < 4; m++) af[m] = *(const short8*)&As[(wm + m * 16 + row) * 32 + kg];
#pragma unroll
    for (int n = 0; n < 4; n++) bfr[n] = *(const short8*)&Bs[(wn + n * 16 + row) * 32 + kg];
#pragma unroll
    for (int m = 0; m < 4; m++)
#pragma unroll
      for (int n = 0; n < 4; n++)
        acc[m][n] = __builtin_amdgcn_mfma_f32_16x16x32_bf16(af[m], bfr[n], acc[m][n], 0, 0, 0);
    __syncthreads();
  }
  const int cr = (lane >> 4) * 4, cc = lane & 15;
  if (EPI == 0) {
    // pi-packed: value of orig col (strip + n*16 + cc) stored at strip + cc*4 + n
    const int cb = tn + wn;  // 64-col strip base
    float bsv[4];
#pragma unroll
    for (int n = 0; n < 4; n++) bsv[n] = bias[cb + n * 16 + cc];
#pragma unroll
    for (int m = 0; m < 4; m++) {
      int rbase = tm + wm + m * 16 + cr;
#pragma unroll
      for (int j = 0; j < 4; j++) {
        u64 pack = (u64)f2bf(acc[m][0][j] + bsv[0])
                 | ((u64)f2bf(acc[m][1][j] + bsv[1]) << 16)
                 | ((u64)f2bf(acc[m][2][j] + bsv[2]) << 32)
                 | ((u64)f2bf(acc[m][3][j] + bsv[3]) << 48);
        *(u64*)&Cb[(size_t)(rbase + j) * 1024 + cb + cc * 4] = pack;
      }
    }
  } else {
#pragma unroll
    for (int m = 0; m < 4; m++) {
#pragma unroll
      for (int n = 0; n < 4; n++) {
        int col = tn + wn + n * 16 + cc;
        float bsv = bias[col];
#pragma unroll
        for (int j = 0; j < 4; j++) {
          int rg = tm + wm + m * 16 + cr + j;
          float v = acc[m][n][j] + bsv;
          int b = rg >> 11, jj = rg & 2047;
          if (jj < 1985) {
            size_t oi = ((size_t)(b << 11) + jj + 63) * 1024 + col;
            Cf[oi] = v + resid[oi];
          }
        }
      }
    }
  }
}

// ---------------- KV projection: 256x256 tile, phased schedule --------------
// C[32768 x 2048] = A @ [WkT|WvT]^T, pi-packed split-write to Ko / Vo.
__launch_bounds__(512, 2)
__global__ void gemm_kv256(const ushort_t* __restrict__ A, const ushort_t* __restrict__ BT,
                           const float* __restrict__ bk, const float* __restrict__ bv,
                           ushort_t* __restrict__ Ko, ushort_t* __restrict__ Vo) {
  __shared__ __attribute__((aligned(16))) ushort_t lds[65536];  // 4 x (A 16KB + B 16KB)
  const int bid = blockIdx.x;                    // 1024 blocks, %8==0 -> bijective swizzle
  const int swz = (bid & 7) * 128 + (bid >> 3);  // XCD chunk swizzle
  const int tm = (swz >> 3) * 256, tn = (swz & 7) * 256;
  const int t = threadIdx.x, lane = t & 63, wv = t >> 6;
  const int wm = wv >> 2, wn = wv & 3;           // 2M x 4N wave grid
  const int row16 = lane & 15, g = lane >> 4;

  const int d1 = t + 512;
  const int ra0 = t >> 2, sa0 = ((t & 3) ^ ((ra0 >> 1) & 3)) * 8;
  const int ra1 = d1 >> 2, sa1 = ((d1 & 3) ^ ((ra1 >> 1) & 3)) * 8;
  const ushort_t* Ag0 = A + (size_t)(tm + ra0) * 1024 + sa0;
  const ushort_t* Ag1 = A + (size_t)(tm + ra1) * 1024 + sa1;
  const ushort_t* Bg0 = BT + (size_t)(tn + ra0) * 1024 + sa0;
  const ushort_t* Bg1 = BT + (size_t)(tn + ra1) * 1024 + sa1;

#define STAGE_A(T) { ushort_t* Ab_ = lds + ((T) & 3) * 16384; const int k0_ = (T) * 32; \
    gl_lds16(Ag0 + k0_, Ab_ + t * 8); gl_lds16(Ag1 + k0_, Ab_ + d1 * 8); }
#define STAGE_B(T) { ushort_t* Bb_ = lds + ((T) & 3) * 16384 + 8192; const int k0_ = (T) * 32; \
    gl_lds16(Bg0 + k0_, Bb_ + t * 8); gl_lds16(Bg1 + k0_, Bb_ + d1 * 8); }

  int aoff[8], boff[4];
#pragma unroll
  for (int m = 0; m < 8; m++) {
    int ra = wm * 128 + m * 16 + row16;
    aoff[m] = ra * 32 + (g ^ ((ra >> 1) & 3)) * 8;
  }
#pragma unroll
  for (int n = 0; n < 4; n++) {
    int rb = wn * 64 + n * 16 + row16;
    boff[n] = rb * 32 + (g ^ ((rb >> 1) & 3)) * 8;
  }

  f32x4 acc[8][4] = {};
  STAGE_A(0); STAGE_B(0); STAGE_A(1); STAGE_B(1);

  for (int T = 0; T < 32; ++T) {
    const ushort_t* Ab = lds + (T & 3) * 16384;
    const ushort_t* Bb = Ab + 8192;
    if (T < 31) { asm volatile("s_waitcnt vmcnt(4)" ::: "memory"); }
    else        { asm volatile("s_waitcnt vmcnt(0)" ::: "memory"); }
    __builtin_amdgcn_s_barrier();

    short8 af[4], bfv[4];
    // ---- phase 0: m-frags 0..3, all B-frags ----
#pragma unroll
    for (int m = 0; m < 4; m++) af[m] = *(const short8*)&Ab[aoff[m]];
#pragma unroll
    for (int n = 0; n < 4; n++) bfv[n] = *(const short8*)&Bb[boff[n]];
    if (T < 30) STAGE_A(T + 2);
    __builtin_amdgcn_s_barrier();
    __builtin_amdgcn_s_setprio(1);
#pragma unroll
    for (int m = 0; m < 4; m++)
#pragma unroll
      for (int n = 0; n < 4; n++)
        acc[m][n] = __builtin_amdgcn_mfma_f32_16x16x32_bf16(af[m], bfv[n], acc[m][n], 0, 0, 0);
    __builtin_amdgcn_s_setprio(0);
    __builtin_amdgcn_s_barrier();

    // ---- phase 1: m-frags 4..7, reuse B-frags ----
#pragma unroll
    for (int m = 0; m < 4; m++) af[m] = *(const short8*)&Ab[aoff[4 + m]];
    if (T < 30) STAGE_B(T + 2);
    __builtin_amdgcn_s_barrier();
    __builtin_amdgcn_s_setprio(1);
#pragma unroll
    for (int m = 0; m < 4; m++)
#pragma unroll
      for (int n = 0; n < 4; n++)
        acc[4 + m][n] = __builtin_amdgcn_mfma_f32_16x16x32_bf16(af[m], bfv[n], acc[4 + m][n], 0, 0, 0);
    __builtin_amdgcn_s_setprio(0);
  }
#undef STAGE_A
#undef STAGE_B

  // pi-packed epilogue: orig col (cb64 + n*16 + row16) stored at cb64 + row16*4 + n.
  const bool isV = (tn >= 1024);
  const float* bias = isV ? bv : bk;
  ushort_t* Out = isV ? Vo : Ko;
  const int cb64 = (isV ? tn - 1024 : tn) + wn * 64;
  float bsv[4];
#pragma unroll
  for (int n = 0; n < 4; n++) bsv[n] = bias[cb64 + n * 16 + row16];
#pragma unroll
  for (int m = 0; m < 8; m++) {
    int rbase = tm + wm * 128 + m * 16 + g * 4;
#pragma unroll
    for (int j = 0; j < 4; j++) {
      u64 pack = (u64)f2bf(acc[m][0][j] + bsv[0])
               | ((u64)f2bf(acc[m][1][j] + bsv[1]) << 16)
               | ((u64)f2bf(acc[m][2][j] + bsv[2]) << 32)
               | ((u64)f2bf(acc[m][3][j] + bsv[3]) << 48);
      *(u64*)&Out[(size_t)(rbase + j) * 1024 + cb64 + row16 * 4] = pack;
    }
  }
}

// ---------------- attention: one block per (b,c,h) --------------------------
// Q,K,V arrive with pi-permuted d-columns (within each head's 64 cols).
// QK^T invariant; V transpose applies pi^-1 so PV output is natural.
__launch_bounds__(256, 2)
__global__ void attn_kernel(const ushort_t* __restrict__ Q, const ushort_t* __restrict__ Kb,
                            const ushort_t* __restrict__ Vb, ushort_t* __restrict__ Ob) {
  __shared__ __attribute__((aligned(16))) ushort_t R0[20480];     // Qs[4096]+Ks[16384]
  __shared__ __attribute__((aligned(16))) ushort_t Vt[64 * 264];  // V^T, padded stride
  ushort_t* Qs = R0;
  ushort_t* Ks = R0 + 4096;
  ushort_t* Sp = R0;  // bf16 S/P [64][264] overlays Qs+Ks after QK^T

  const int hh = blockIdx.x, cch = blockIdx.y, b = blockIdx.z;
  const int t = threadIdx.x, lane = t & 63, wv = t >> 6;
  const size_t qbase = ((size_t)(b * 32 + cch) * 64) * 1024 + hh * 64;
  const size_t kvbase = ((size_t)(b * 32 + cch) * 256) * 1024 + hh * 64;

  {
    int ch = t, r = ch >> 3, gq = (ch & 7) ^ (r & 7);
    gl_lds16(Q + qbase + (size_t)r * 1024 + gq * 8, &Qs[ch * 8]);
    ch = t + 256; r = ch >> 3; gq = (ch & 7) ^ (r & 7);
    gl_lds16(Q + qbase + (size_t)r * 1024 + gq * 8, &Qs[ch * 8]);
  }
#pragma unroll
  for (int p = 0; p < 8; p++) {
    int ch = t + 256 * p;
    int r = ch >> 3, gq = (ch & 7) ^ (r & 7);
    gl_lds16(Kb + kvbase + (size_t)r * 1024 + gq * 8, &Ks[ch * 8]);
  }
  // V transposed into Vt[d_orig][j]: stored position p -> orig ((p&3)<<4)|(p>>2)
#pragma unroll
  for (int p = 0; p < 8; p++) {
    int ch = t + 256 * p;
    int j = ch >> 3, d0 = (ch & 7) * 8;
    short8 vv = *(const short8*)(Vb + kvbase + (size_t)j * 1024 + d0);
#pragma unroll
    for (int ii = 0; ii < 8; ii++) {
      int pp = d0 + ii;
      int od = ((pp & 3) << 4) | (pp >> 2);
      Vt[od * 264 + j] = (ushort_t)vv[ii];
    }
  }
  __syncthreads();

  const int row = lane & 15, kg = (lane >> 4) * 8;
  const int cswz = (row & 7) << 3;
  f32x4 accs[4][4] = {};
#pragma unroll
  for (int kk = 0; kk < 64; kk += 32) {
    int cq = ((kk + kg) ^ cswz);
    short8 af[4], bfr[4];
#pragma unroll
    for (int m = 0; m < 4; m++) af[m] = *(const short8*)&Qs[(m * 16 + row) * 64 + cq];
#pragma unroll
    for (int n = 0; n < 4; n++)
      bfr[n] = *(const short8*)&Ks[(wv * 64 + n * 16 + row) * 64 + cq];
#pragma unroll
    for (int m = 0; m < 4; m++)
#pragma unroll
      for (int n = 0; n < 4; n++)
        accs[m][n] = __builtin_amdgcn_mfma_f32_16x16x32_bf16(af[m], bfr[n], accs[m][n], 0, 0, 0);
  }
  __syncthreads();

  {
    const int cr = (lane >> 4) * 4, cc = lane & 15;
#pragma unroll
    for (int m = 0; m < 4; m++)
#pragma unroll
      for (int n = 0; n < 4; n++)
#pragma unroll
        for (int j = 0; j < 4; j++)
          Sp[(m * 16 + cr + j) * 264 + wv * 64 + n * 16 + cc] = f2bf(accs[m][n][j]);
  }
  __syncthreads();

  {
    const int r = t >> 2, q = t & 3;
    const int base = r * 264 + q * 64;
    float ev[64];
#pragma unroll
    for (int p = 0; p < 8; p++) {
      short8 sv = *(const short8*)&Sp[base + p * 8];
#pragma unroll
      for (int i = 0; i < 8; i++) ev[p * 8 + i] = bf2f((ushort_t)sv[i]);
    }
    float mx = ev[0];
#pragma unroll
    for (int i = 1; i < 64; i++) mx = fmaxf(mx, ev[i]);
    mx = fmaxf(mx, __shfl_xor(mx, 1));
    mx = fmaxf(mx, __shfl_xor(mx, 2));
    float sum = 0.f;
#pragma unroll
    for (int i = 0; i < 64; i++) {
      ev[i] = __expf((ev[i] - mx) * 0.125f);
      sum += ev[i];
    }
    sum += __shfl_xor(sum, 1);
    sum += __shfl_xor(sum, 2);
    float inv = 1.f / sum;
#pragma unroll
    for (int p = 0; p < 8; p++) {
      short8 pv;
#pragma unroll
      for (int i = 0; i < 8; i++) pv[i] = (short)f2bf(ev[p * 8 + i] * inv);
      *(short8*)&Sp[base + p * 8] = pv;
    }
  }
  __syncthreads();

  {
    f32x4 acco[4] = {};
#pragma unroll
    for (int kt = 0; kt < 8; kt++) {
      short8 bfv = *(const short8*)&Vt[(wv * 16 + row) * 264 + kt * 32 + kg];
#pragma unroll
      for (int m = 0; m < 4; m++) {
        short8 af = *(const short8*)&Sp[(m * 16 + row) * 264 + kt * 32 + kg];
        acco[m] = __builtin_amdgcn_mfma_f32_16x16x32_bf16(af, bfv, acco[m], 0, 0, 0);
      }
    }
    const int cr = (lane >> 4) * 4, cc = lane & 15;
    size_t obase = ((size_t)(b * 32 + cch) * 64) * 1024 + hh * 64 + wv * 16 + cc;
#pragma unroll
    for (int m = 0; m < 4; m++)
#pragma unroll
      for (int j = 0; j < 4; j++)
        Ob[obase + (size_t)(m * 16 + cr + j) * 1024] = f2bf(acco[m][j]);
  }
}

// ---------------- residual-only prologue rows t < 63 ------------------------
__global__ void copy_prologue(const float* __restrict__ h, float* __restrict__ out) {
  int tt = blockIdx.x;  // 0..251
  int b = tt / 63, r = tt % 63;
  size_t idx = ((size_t)(b * 2048) + r) * 1024 + threadIdx.x * 4;
  *(f32x4*)&out[idx] = *(const f32x4*)&h[idx];
}

extern "C" void kernel_launch(void* const* d_in, const int* in_sizes, int n_in,
                              void* d_out, int out_size, void* d_ws, size_t ws_size,
                              hipStream_t stream) {
  const float* h    = (const float*)d_in[0];
  const float* e    = (const float*)d_in[1];
  const float* ln_g = (const float*)d_in[2];
  const float* ln_b = (const float*)d_in[3];
  const float* Wq   = (const float*)d_in[4];
  const float* bq   = (const float*)d_in[5];
  const float* Wk   = (const float*)d_in[6];
  const float* bk   = (const float*)d_in[7];
  const float* Wv   = (const float*)d_in[8];
  const float* bv   = (const float*)d_in[9];
  const float* Wo   = (const float*)d_in[10];
  const float* bo   = (const float*)d_in[11];
  float* out = (float*)d_out;

  char* ws = (char*)d_ws;
  const size_t MB = 1024 * 1024;
  ushort_t* WqT  = (ushort_t*)(ws + 0 * MB);
  ushort_t* WkT  = (ushort_t*)(ws + 2 * MB);   // WkT || WvT contiguous = BT[2048][1024]
  ushort_t* WvT  = (ushort_t*)(ws + 4 * MB);
  ushort_t* WoT  = (ushort_t*)(ws + 6 * MB);
  ushort_t* hb   = (ushort_t*)(ws + 8 * MB);    // 16 MB
  ushort_t* e_bf = (ushort_t*)(ws + 24 * MB);   // 64 MB
  ushort_t* Qb   = (ushort_t*)(ws + 88 * MB);   // 16 MB
  ushort_t* Kbuf = (ushort_t*)(ws + 104 * MB);  // 64 MB
  ushort_t* Vbuf = (ushort_t*)(ws + 168 * MB);  // 64 MB
  ushort_t* Obuf = (ushort_t*)(ws + 232 * MB);  // 16 MB -> total 248 MB

  dim3 g32(32, 32);
  transpose_w<<<g32, 256, 0, stream>>>(Wq, WqT);
  transpose_w<<<g32, 256, 0, stream>>>(Wk, WkT);
  transpose_w<<<g32, 256, 0, stream>>>(Wv, WvT);
  transpose_w<<<g32, 256, 0, stream>>>(Wo, WoT);

  ln_kernel<<<8192, 256, 0, stream>>>(h, ln_g, ln_b, hb);
  conv_bf16<<<16384, 256, 0, stream>>>(e, e_bf, 4194304);  // 32768*1024/8

  gemm_bt<0><<<512, 256, 0, stream>>>(hb, WqT, bq, Qb, nullptr, nullptr);
  gemm_kv256<<<1024, 512, 0, stream>>>(e_bf, WkT, bk, bv, Kbuf, Vbuf);

  attn_kernel<<<dim3(16, 32, 4), 256, 0, stream>>>(Qb, Kbuf, Vbuf, Obuf);

  gemm_bt<1><<<512, 256, 0, stream>>>(Obuf, WoT, bo, nullptr, out, h);
  copy_prologue<<<252, 256, 0, stream>>>(h, out);
}